// Round 10
// baseline (164.934 us; speedup 1.0000x reference)
//
#include <hip/hip_runtime.h>

typedef unsigned int uint;
typedef _Float16 f16x2 __attribute__((ext_vector_type(2)));

#define B_ 64
#define T_ 512
#define K_ 10
constexpr float TEMP_ = 0.07f;
constexpr float EPS_ = 1e-8f;
constexpr int F4ROW = 256;          // float4 per 1024-f32 row
constexpr int NPAIR = 255;          // valid anchor pairs per b: u = 1+2c, c in [0,255)
constexpr int PBLK = 64;            // pair-slots per b / 4 waves = 64 blocks per b
constexpr int ROWU = 512;           // packed uints per neg row (2 f16 each)

__device__ __forceinline__ float dot4(float4 a, float4 b) {
    return a.x * b.x + a.y * b.y + a.z * b.z + a.w * b.w;
}
__device__ __forceinline__ f16x2 bc_(uint u){ return __builtin_bit_cast(f16x2, u); }
__device__ __forceinline__ f16x2 pkrtz(float a, float b){
    return __builtin_bit_cast(f16x2, __builtin_amdgcn_cvt_pkrtz(a, b));
}
__device__ __forceinline__ uint pkrtz_u(float a, float b){
    return __builtin_bit_cast(uint, __builtin_amdgcn_cvt_pkrtz(a, b));
}

// ---- DPP-only wave reduction ----
template <int CTRL>
__device__ __forceinline__ float dpp_add(float x){
    int y = __builtin_amdgcn_update_dpp(0, __float_as_int(x), CTRL, 0xf, 0xf, false);
    return x + __int_as_float(y);
}
// sum over 64 lanes, result valid on lanes 48..63 ONLY (pure VALU, no LDS pipe)
__device__ __forceinline__ float red6(float x){
    x = dpp_add<0x128>(x);      // row_ror:8
    x = dpp_add<0x124>(x);      // row_ror:4
    x = dpp_add<0x122>(x);      // row_ror:2
    x = dpp_add<0x121>(x);      // row_ror:1   -> each 16-row holds its sum
    x = dpp_add<0x142>(x);      // row_bcast15 -> row1=s01, row3=s23
    x = dpp_add<0x143>(x);      // row_bcast31 -> row3=total
    return x;
}
__device__ __forceinline__ float red64(float x){
    x = red6(x);
    return __shfl(x, 63, 64);
}

// ---- prep: one wave per (b,k); unit negs, f16-pair-packed, lane-permuted ----
// also zeroes the accumulator + completion counter for this call
__global__ __launch_bounds__(64) void signcl_prep(
    const float* __restrict__ features,
    const int* __restrict__ neg_b,
    const int* __restrict__ neg_t,
    uint* __restrict__ negs_pk,
    float* __restrict__ accum,
    uint* __restrict__ counter)
{
    const int blk = blockIdx.x;
    const int b = blk / K_, k = blk % K_;
    const int l = threadIdx.x;

    if (blk == 0 && l == 0){ accum[0] = 0.f; counter[0] = 0u; }

    const int nb = neg_b[b * K_ + k];
    const int nt = neg_t[b * K_ + k];
    const float4* rp = reinterpret_cast<const float4*>(features)
                       + ((size_t)nb * T_ + nt) * F4ROW + l * 4;
    float4 v0 = rp[0], v1 = rp[1], v2 = rp[2], v3 = rp[3];
    float ss = dot4(v0, v0) + dot4(v1, v1) + dot4(v2, v2) + dot4(v3, v3);
    ss = red64(ss);
    const float inv = 1.f / fmaxf(sqrtf(ss), EPS_);

    uint4* out = reinterpret_cast<uint4*>(negs_pk + ((size_t)b * K_ + k) * ROWU);
    uint4 o;
    o.x = pkrtz_u(v0.x * inv, v0.y * inv);
    o.y = pkrtz_u(v0.z * inv, v0.w * inv);
    o.z = pkrtz_u(v1.x * inv, v1.y * inv);
    o.w = pkrtz_u(v1.z * inv, v1.w * inv);
    out[l] = o;
    o.x = pkrtz_u(v2.x * inv, v2.y * inv);
    o.y = pkrtz_u(v2.z * inv, v2.w * inv);
    o.z = pkrtz_u(v3.x * inv, v3.y * inv);
    o.w = pkrtz_u(v3.z * inv, v3.w * inv);
    out[64 + l] = o;
}

#define PACK8(F, X0, X1, X2, X3)                              \
    F##0 = pkrtz(X0.x, X0.y);                                 \
    F##1 = pkrtz(X0.z, X0.w);                                 \
    F##2 = pkrtz(X1.x, X1.y);                                 \
    F##3 = pkrtz(X1.z, X1.w);                                 \
    F##4 = pkrtz(X2.x, X2.y);                                 \
    F##5 = pkrtz(X2.z, X2.w);                                 \
    F##6 = pkrtz(X3.x, X3.y);                                 \
    F##7 = pkrtz(X3.z, X3.w);

// ---- main: wave-per-pair in 256-thread blocks; no staging; fused final reduce ----
__global__ __launch_bounds__(256, 2) void signcl_main(
    const float* __restrict__ features,
    const uint* __restrict__ negs_pk,
    float* __restrict__ accum,
    uint* __restrict__ counter,
    float* __restrict__ out)
{
    __shared__ float s_part[4];
    const int tid = threadIdx.x;
    const int l = tid & 63, w = tid >> 6;   // lane owns cols [16l, 16l+16)
    const int b = blockIdx.y;               // 0..63
    const int c = blockIdx.x * 4 + w;       // pair slot 0..255; c==255 invalid

    float lsum = 0.f;
    if (c < NPAIR){
        const int u = 1 + 2 * c;            // anchors u (A,B), u+1 (B,C); rows <= 510+1
        const float4* fb = reinterpret_cast<const float4*>(features) + (size_t)b * T_ * F4ROW;
        const float4* rA = fb + (size_t)u * F4ROW + l * 4;
        const float4* rB = rA + F4ROW;
        const float4* rC = rB + F4ROW;
        float4 A0 = rA[0], A1 = rA[1], A2 = rA[2], A3 = rA[3];
        float4 B0 = rB[0], B1 = rB[1], B2 = rB[2], B3 = rB[3];
        float4 C0 = rC[0], C1 = rC[1], C2 = rC[2], C3 = rC[3];

        const uint4* n4 = reinterpret_cast<const uint4*>(negs_pk + (size_t)b * K_ * ROWU);

        f16x2 FA0, FA1, FA2, FA3, FA4, FA5, FA6, FA7;
        f16x2 FB0, FB1, FB2, FB3, FB4, FB5, FB6, FB7;
        PACK8(FA, A0, A1, A2, A3);
        PACK8(FB, B0, B1, B2, B3);

        // 10 neg sims for both anchors; coalesced L2 reads shared across the pair
        float ndu[K_], ndv[K_];
#pragma unroll
        for (int k = 0; k < K_; ++k){
            uint4 u0 = n4[k * 128 + l];         // cols [16l, 16l+8)
            uint4 u1 = n4[k * 128 + 64 + l];    // cols [16l+8, 16l+16)
            float su = 0.f, sv = 0.f;
            f16x2 e;
            e = bc_(u0.x); su = __builtin_amdgcn_fdot2(FA0, e, su, false); sv = __builtin_amdgcn_fdot2(FB0, e, sv, false);
            e = bc_(u0.y); su = __builtin_amdgcn_fdot2(FA1, e, su, false); sv = __builtin_amdgcn_fdot2(FB1, e, sv, false);
            e = bc_(u0.z); su = __builtin_amdgcn_fdot2(FA2, e, su, false); sv = __builtin_amdgcn_fdot2(FB2, e, sv, false);
            e = bc_(u0.w); su = __builtin_amdgcn_fdot2(FA3, e, su, false); sv = __builtin_amdgcn_fdot2(FB3, e, sv, false);
            e = bc_(u1.x); su = __builtin_amdgcn_fdot2(FA4, e, su, false); sv = __builtin_amdgcn_fdot2(FB4, e, sv, false);
            e = bc_(u1.y); su = __builtin_amdgcn_fdot2(FA5, e, su, false); sv = __builtin_amdgcn_fdot2(FB5, e, sv, false);
            e = bc_(u1.z); su = __builtin_amdgcn_fdot2(FA6, e, su, false); sv = __builtin_amdgcn_fdot2(FB6, e, sv, false);
            e = bc_(u1.w); su = __builtin_amdgcn_fdot2(FA7, e, su, false); sv = __builtin_amdgcn_fdot2(FB7, e, sv, false);
            ndu[k] = su; ndv[k] = sv;
        }

        float ssA  = dot4(A0, A0) + dot4(A1, A1) + dot4(A2, A2) + dot4(A3, A3);
        float ssB  = dot4(B0, B0) + dot4(B1, B1) + dot4(B2, B2) + dot4(B3, B3);
        float ssC  = dot4(C0, C0) + dot4(C1, C1) + dot4(C2, C2) + dot4(C3, C3);
        float dpAB = dot4(A0, B0) + dot4(A1, B1) + dot4(A2, B2) + dot4(A3, B3);
        float dpBC = dot4(B0, C0) + dot4(B1, C1) + dot4(B2, C2) + dot4(B3, C3);

#pragma unroll
        for (int k = 0; k < K_; ++k){ ndu[k] = red6(ndu[k]); ndv[k] = red6(ndv[k]); }
        ssA = red6(ssA); ssB = red6(ssB); ssC = red6(ssC);
        dpAB = red6(dpAB); dpBC = red6(dpBC);

        // epilogue (valid on lanes 48..63; lane 63's value is used)
        const float invT = 1.f / TEMP_;
        const float invA = 1.f / fmaxf(sqrtf(ssA), EPS_);
        const float invB = 1.f / fmaxf(sqrtf(ssB), EPS_);
        const float invC = 1.f / fmaxf(sqrtf(ssC), EPS_);
        {
            float pos = dpAB * invA * invB * invT;
            float sc = invA * invT;
            float se = 0.f;
#pragma unroll
            for (int k = 0; k < K_; ++k) se += __expf(ndu[k] * sc);
            lsum = __logf(__expf(pos) + se) - pos;
        }
        {
            float pos = dpBC * invB * invC * invT;
            float sc = invB * invT;
            float se = 0.f;
#pragma unroll
            for (int k = 0; k < K_; ++k) se += __expf(ndv[k] * sc);
            lsum += __logf(__expf(pos) + se) - pos;
        }
    }

    if (l == 63) s_part[w] = lsum;          // lane 63 holds the valid pair sum
    __syncthreads();
    if (tid == 0){
        float p = s_part[0] + s_part[1] + s_part[2] + s_part[3];
        atomicAdd(accum, p);                // device-scope by default
        __threadfence();
        uint prev = atomicAdd(counter, 1u);
        if (prev == (uint)(gridDim.x * gridDim.y - 1)){
            float t = atomicAdd(accum, 0.f);   // atomic read: all adds serialized in L2
            out[0] = t / (float)(B_ * (T_ - 2));
        }
    }
}

extern "C" void kernel_launch(void* const* d_in, const int* in_sizes, int n_in,
                              void* d_out, int out_size, void* d_ws, size_t ws_size,
                              hipStream_t stream) {
    const float* features = (const float*)d_in[0];
    const int* neg_b = (const int*)d_in[1];
    const int* neg_t = (const int*)d_in[2];
    uint* negs_pk = (uint*)d_ws;                               // 1.31 MB packed negs
    float* accum = (float*)((char*)d_ws + (2u << 20));         // scalar accumulator
    uint* counter = (uint*)((char*)d_ws + (2u << 20) + 256);   // completion counter

    signcl_prep<<<B_ * K_, 64, 0, stream>>>(features, neg_b, neg_t, negs_pk, accum, counter);
    signcl_main<<<dim3(PBLK, B_), 256, 0, stream>>>(features, negs_pk, accum, counter, (float*)d_out);
}

// Round 11
// 44.136 us; speedup vs baseline: 3.7370x; 3.7370x over previous
//
#include <hip/hip_runtime.h>

typedef unsigned int uint;

#define B_ 64
#define T_ 512
#define K_ 10
constexpr float TEMP_ = 0.07f;
constexpr float EPS_ = 1e-8f;
constexpr int F4ROW = 256;          // float4 per 1024-f32 row
constexpr int APW = 4;              // anchors per wave
constexpr int NBLK = 32;            // blocks per b (4 waves * 4 anchors = 16 anchors/block)
constexpr int ROWU = 512;           // packed uints per neg row (2 bf16 each)

__device__ __forceinline__ float dot4(float4 a, float4 b) {
    return a.x * b.x + a.y * b.y + a.z * b.z + a.w * b.w;
}
__device__ __forceinline__ float plo_(uint u){ return __uint_as_float(u << 16); }
__device__ __forceinline__ float phi_(uint u){ return __uint_as_float(u & 0xffff0000u); }
__device__ __forceinline__ uint bfr_(float f){
    uint u = __float_as_uint(f);
    return (u + 0x7fffu + ((u >> 16) & 1u)) >> 16;
}
__device__ __forceinline__ uint pack2_(float lo, float hi){ return bfr_(lo) | (bfr_(hi) << 16); }

// 64-lane all-reduce: 4x DPP row_ror (16-lane) + ds_swizzle xor16 + shfl_xor 32
template <int CTRL>
__device__ __forceinline__ float dpp_add(float x){
    int y = __builtin_amdgcn_update_dpp(0, __float_as_int(x), CTRL, 0xf, 0xf, false);
    return x + __int_as_float(y);
}
__device__ __forceinline__ float red64(float x){
    x = dpp_add<0x128>(x);
    x = dpp_add<0x124>(x);
    x = dpp_add<0x122>(x);
    x = dpp_add<0x121>(x);
    int y = __builtin_amdgcn_ds_swizzle(__float_as_int(x), 0x401F); // xor lane^16
    x += __int_as_float(y);
    x += __shfl_xor(x, 32, 64);
    return x;
}

// ---- prep: one wave per (b,k); normalized bf16-packed neg rows in lane-permuted order ----
// layout per row: uint4 index (h*64 + l) holds cols [16l+8h, 16l+8h+8) as 4 bf16-pairs
__global__ __launch_bounds__(64) void signcl_prep(
    const float* __restrict__ features,
    const int* __restrict__ neg_b,
    const int* __restrict__ neg_t,
    uint* __restrict__ negs_pk)
{
    const int blk = blockIdx.x;
    const int b = blk / K_, k = blk % K_;
    const int l = threadIdx.x;              // 0..63

    const int nb = neg_b[b * K_ + k];
    const int nt = neg_t[b * K_ + k];
    const float4* rp = reinterpret_cast<const float4*>(features)
                       + ((size_t)nb * T_ + nt) * F4ROW + l * 4;
    float4 v0 = rp[0], v1 = rp[1], v2 = rp[2], v3 = rp[3];
    float ss = dot4(v0, v0) + dot4(v1, v1) + dot4(v2, v2) + dot4(v3, v3);
    ss = red64(ss);
    const float inv = 1.f / fmaxf(sqrtf(ss), EPS_);

    uint4* out = reinterpret_cast<uint4*>(negs_pk + ((size_t)b * K_ + k) * ROWU);
    uint4 o;
    o.x = pack2_(v0.x * inv, v0.y * inv);
    o.y = pack2_(v0.z * inv, v0.w * inv);
    o.z = pack2_(v1.x * inv, v1.y * inv);
    o.w = pack2_(v1.z * inv, v1.w * inv);
    out[l] = o;
    o.x = pack2_(v2.x * inv, v2.y * inv);
    o.y = pack2_(v2.z * inv, v2.w * inv);
    o.z = pack2_(v3.x * inv, v3.y * inv);
    o.w = pack2_(v3.z * inv, v3.w * inv);
    out[64 + l] = o;
}

// ---- main: LDS-resident packed negs, register double-buffered row walk ----
__global__ __launch_bounds__(256) void signcl_main(
    const float* __restrict__ features,
    const uint* __restrict__ negs_pk,
    float* __restrict__ partials)
{
    __shared__ uint s_negs[K_ * ROWU];      // 20480 B
    __shared__ float s_part[4];

    const int tid = threadIdx.x;
    const int l = tid & 63, w = tid >> 6;
    const int bid = blockIdx.x;
    const int b = bid >> 5;                 // / NBLK
    const int c = bid & (NBLK - 1);

    // stage packed negs (contiguous vector copy)
    {
        const uint4* gsrc = reinterpret_cast<const uint4*>(negs_pk + (size_t)b * K_ * ROWU);
        uint4* sdst = reinterpret_cast<uint4*>(s_negs);
#pragma unroll
        for (int j = 0; j < 5; ++j) sdst[tid + j * 256] = gsrc[tid + j * 256];
    }
    __syncthreads();

    const float4* fb = reinterpret_cast<const float4*>(features) + (size_t)b * T_ * F4ROW;
    const uint4* n4 = reinterpret_cast<const uint4*>(s_negs);
    const int ta = 1 + c * 16 + w * APW;    // 1..509; slots t=1..512, valid t<=510

    const float4* rp = fb + (size_t)ta * F4ROW + l * 4;
    float4 A0 = rp[0], A1 = rp[1], A2 = rp[2], A3 = rp[3];
    float ssc = dot4(A0, A0) + dot4(A1, A1) + dot4(A2, A2) + dot4(A3, A3);
    float inv_c = 1.f / fmaxf(sqrtf(red64(ssc)), EPS_);

    const float invT = 1.f / TEMP_;
    float lsum = 0.f;

#pragma unroll
    for (int i = 0; i < APW; ++i){
        const int t = ta + i;
        const int tn = (t + 1 < T_ - 1) ? (t + 1) : (T_ - 1);
        const float4* rn = fb + (size_t)tn * F4ROW + l * 4;
        float4 N0 = rn[0], N1 = rn[1], N2 = rn[2], N3 = rn[3];   // issued early

        // 10 neg dots on cur only (hides the N-load latency)
        float nd[K_];
#pragma unroll
        for (int k = 0; k < K_; ++k){
            uint4 u0 = n4[k * 128 + l];        // cols [16l, 16l+8)
            uint4 u1 = n4[k * 128 + 64 + l];   // cols [16l+8, 16l+16)
            float a;
            a = fmaf(A0.x, plo_(u0.x), 0.f);
            a = fmaf(A0.y, phi_(u0.x), a);
            a = fmaf(A0.z, plo_(u0.y), a);
            a = fmaf(A0.w, phi_(u0.y), a);
            a = fmaf(A1.x, plo_(u0.z), a);
            a = fmaf(A1.y, phi_(u0.z), a);
            a = fmaf(A1.z, plo_(u0.w), a);
            a = fmaf(A1.w, phi_(u0.w), a);
            a = fmaf(A2.x, plo_(u1.x), a);
            a = fmaf(A2.y, phi_(u1.x), a);
            a = fmaf(A2.z, plo_(u1.y), a);
            a = fmaf(A2.w, phi_(u1.y), a);
            a = fmaf(A3.x, plo_(u1.z), a);
            a = fmaf(A3.y, phi_(u1.z), a);
            a = fmaf(A3.z, plo_(u1.w), a);
            a = fmaf(A3.w, phi_(u1.w), a);
            nd[k] = a;
        }
#pragma unroll
        for (int k = 0; k < K_; ++k) nd[k] = red64(nd[k]);

        float ssn = dot4(N0, N0) + dot4(N1, N1) + dot4(N2, N2) + dot4(N3, N3);
        float dp  = dot4(A0, N0) + dot4(A1, N1) + dot4(A2, N2) + dot4(A3, N3);
        ssn = red64(ssn);
        dp  = red64(dp);
        const float inv_n = 1.f / fmaxf(sqrtf(ssn), EPS_);

        if (t <= T_ - 2){
            float pos = dp * inv_c * inv_n * invT;
            float sc = inv_c * invT;
            float se = 0.f;
#pragma unroll
            for (int k = 0; k < K_; ++k) se += __expf(nd[k] * sc);
            lsum += __logf(__expf(pos) + se) - pos;
        }
        A0 = N0; A1 = N1; A2 = N2; A3 = N3; inv_c = inv_n;
    }

    if (l == 0) s_part[w] = lsum;           // identical across lanes post-red64
    __syncthreads();
    if (tid == 0) partials[bid] = s_part[0] + s_part[1] + s_part[2] + s_part[3];
}

__global__ __launch_bounds__(256) void signcl_reduce(
    const float* __restrict__ partials, float* __restrict__ out)
{
    __shared__ float s_w[4];
    const int tid = threadIdx.x;
    float s = 0.f;
    for (int idx = tid; idx < B_ * NBLK; idx += 256) s += partials[idx];
#pragma unroll
    for (int m = 32; m >= 1; m >>= 1) s += __shfl_xor(s, m, 64);
    const int w = tid >> 6, lane = tid & 63;
    if (lane == 0) s_w[w] = s;
    __syncthreads();
    if (tid == 0) {
        float t = s_w[0] + s_w[1] + s_w[2] + s_w[3];
        out[0] = t / (float)(B_ * (T_ - 2));
    }
}

extern "C" void kernel_launch(void* const* d_in, const int* in_sizes, int n_in,
                              void* d_out, int out_size, void* d_ws, size_t ws_size,
                              hipStream_t stream) {
    const float* features = (const float*)d_in[0];
    const int* neg_b = (const int*)d_in[1];
    const int* neg_t = (const int*)d_in[2];
    uint* negs_pk = (uint*)d_ws;                               // 1.31 MB packed negs
    float* partials = (float*)((char*)d_ws + (2u << 20));      // 2048 floats at +2 MB

    signcl_prep<<<B_ * K_, 64, 0, stream>>>(features, neg_b, neg_t, negs_pk);
    signcl_main<<<B_ * NBLK, 256, 0, stream>>>(features, negs_pk, partials);
    signcl_reduce<<<1, 256, 0, stream>>>(partials, (float*)d_out);
}